// Round 1
// baseline (436.350 us; speedup 1.0000x reference)
//
#include <hip/hip_runtime.h>

// out[i,j,k] = image[i,j,perm[i,j,k]], C=3, W=H=4096.
// Memory-bound gather: 4 pixels/thread = 12 floats = 3x float4 (48B group,
// 16B aligned). Perm values in {0,1,2} -> two v_cndmask per output element.

__global__ __launch_bounds__(256) void PerPixelChannelPermutation_kernel(
    const float4* __restrict__ img4, const int4* __restrict__ perm4,
    float4* __restrict__ out4, int nthreads) {
    int t = blockIdx.x * blockDim.x + threadIdx.x;
    if (t >= nthreads) return;
    int base = t * 3;

    float4 i0 = img4[base + 0];
    float4 i1 = img4[base + 1];
    float4 i2 = img4[base + 2];
    int4   q0 = perm4[base + 0];
    int4   q1 = perm4[base + 1];
    int4   q2 = perm4[base + 2];

    float a[12] = {i0.x, i0.y, i0.z, i0.w,
                   i1.x, i1.y, i1.z, i1.w,
                   i2.x, i2.y, i2.z, i2.w};
    int   p[12] = {q0.x, q0.y, q0.z, q0.w,
                   q1.x, q1.y, q1.z, q1.w,
                   q2.x, q2.y, q2.z, q2.w};
    float o[12];

#pragma unroll
    for (int px = 0; px < 4; ++px) {
        const float c0 = a[3 * px + 0];
        const float c1 = a[3 * px + 1];
        const float c2 = a[3 * px + 2];
#pragma unroll
        for (int k = 0; k < 3; ++k) {
            const int pk = p[3 * px + k];
            // pk in {0,1,2}: two selects, stays in registers (indices are
            // compile-time constants after unroll).
            o[3 * px + k] = (pk == 0) ? c0 : ((pk == 1) ? c1 : c2);
        }
    }

    out4[base + 0] = make_float4(o[0], o[1], o[2], o[3]);
    out4[base + 1] = make_float4(o[4], o[5], o[6], o[7]);
    out4[base + 2] = make_float4(o[8], o[9], o[10], o[11]);
}

extern "C" void kernel_launch(void* const* d_in, const int* in_sizes, int n_in,
                              void* d_out, int out_size, void* d_ws, size_t ws_size,
                              hipStream_t stream) {
    const float4* img4  = (const float4*)d_in[0];
    const int4*   perm4 = (const int4*)d_in[1];
    float4*       out4  = (float4*)d_out;

    const int n_elems  = in_sizes[0];      // 4096*4096*3, divisible by 12
    const int nthreads = n_elems / 12;     // 4 pixels (12 floats) per thread

    const int block = 256;
    const int grid  = (nthreads + block - 1) / block;
    PerPixelChannelPermutation_kernel<<<grid, block, 0, stream>>>(
        img4, perm4, out4, nthreads);
}